// Round 5
// baseline (710.834 us; speedup 1.0000x reference)
//
#include <hip/hip_runtime.h>
#include <math.h>

#define NN 50000
#define NE 800000

typedef __attribute__((ext_vector_type(8))) short short8;
typedef __attribute__((ext_vector_type(4))) float floatx4;

__device__ __forceinline__ unsigned short bf16_of(float x) {
  unsigned u = __float_as_uint(x);
  u += 0x7fffu + ((u >> 16) & 1u);
  return (unsigned short)(u >> 16);
}
__device__ __forceinline__ float bf2f(unsigned short u) {
  return __uint_as_float(((unsigned)u) << 16);
}
__device__ __forceinline__ unsigned pack_bf(float a, float b) {
  unsigned ua = __float_as_uint(a); ua += 0x7fffu + ((ua >> 16) & 1u);
  unsigned ub = __float_as_uint(b); ub += 0x7fffu + ((ub >> 16) & 1u);
  return (ua >> 16) | (ub & 0xffff0000u);
}
__device__ __forceinline__ float blo(unsigned w) { return __uint_as_float(w << 16); }
__device__ __forceinline__ float bhi(unsigned w) { return __uint_as_float(w & 0xffff0000u); }

// ---------------- norm over all edges + degree count ----------------
__global__ __launch_bounds__(256)
void k_radnorm(const float* __restrict__ coord, const int* __restrict__ row,
               const int* __restrict__ col, float* __restrict__ norm_acc,
               int* __restrict__ deg) {
  const int lane = threadIdx.x & 63;
  const int cf = lane & 15;
  const int eg = lane >> 4;
  const int c4 = cf >> 2, f4 = cf & 3;
  const int wid = blockIdx.x * (blockDim.x >> 6) + (threadIdx.x >> 6);
  const int nw = gridDim.x * (blockDim.x >> 6);
  float acc = 0.f;
  for (int base = wid * 4; base < NE; base += nw * 4) {
    int e = base + eg;
    int r = row[e], c = col[e];
    const float* cr = coord + r * 12;
    const float* cc = coord + c * 12;
    float rad = 0.f;
#pragma unroll
    for (int d = 0; d < 3; ++d) {
      float a = cr[c4 * 3 + d] - cc[c4 * 3 + d];
      float b = cr[f4 * 3 + d] - cc[f4 * 3 + d];
      rad += a * b;
    }
    acc += rad * rad;
    if (cf == 0) atomicAdd(deg + r, 1);
  }
  acc += __shfl_xor(acc, 16);
  acc += __shfl_xor(acc, 32);
  if (lane < 16) atomicAdd(norm_acc + cf, acc);
}

// ---------------- weight pre-conversion (once) ----------------
__global__ __launch_bounds__(256)
void k_prep(const float* __restrict__ Wkv, const float* __restrict__ W1,
            const float* __restrict__ Wq, unsigned short* __restrict__ Bkvb,
            unsigned short* __restrict__ W1tb, unsigned* __restrict__ Wqp) {
  const int gid = blockIdx.x * 256 + threadIdx.x;
  const int np = gridDim.x * 256;
  for (int idx = gid; idx < 128 * 96; idx += np) {
    int n = idx & 127, kk = idx >> 7;
    float w = (n < 64) ? Wkv[kk * 128 + 2 * n] : Wkv[kk * 128 + 2 * (n - 64) + 1];
    Bkvb[n * 104 + kk] = bf16_of(w);
  }
  for (int idx = gid; idx < 64 * 64; idx += np) {
    int n = idx & 63, kk = idx >> 6;
    W1tb[n * 88 + kk] = bf16_of(W1[kk * 64 + n]);
  }
  for (int idx = gid; idx < 32 * 64; idx += np) {
    int i2 = idx >> 6, j = idx & 63;
    Wqp[idx] = pack_bf(Wq[(2 * i2) * 64 + j], Wq[(2 * i2 + 1) * 64 + j]);
  }
}

// ---------------- CSR scan (+ rnorm finalize folded in) ----------------
__global__ void k_scan(const int* __restrict__ deg, int* __restrict__ startA,
                       int* __restrict__ cursor, const float* __restrict__ norm_acc,
                       float* __restrict__ rnorm) {
  __shared__ int part[1024];
  const int t = threadIdx.x;
  if (t < 16) rnorm[t] = 1.0f / fmaxf(sqrtf(norm_acc[t]), 1e-12f);
  const int CH = (NN + 1023) / 1024;
  const int lo = t * CH, hi = (lo + CH < NN) ? lo + CH : NN;
  int s = 0;
  for (int i = lo; i < hi; ++i) s += deg[i];
  part[t] = s;
  __syncthreads();
  for (int off = 1; off < 1024; off <<= 1) {
    int v = (t >= off) ? part[t - off] : 0;
    __syncthreads();
    part[t] += v;
    __syncthreads();
  }
  int base = (t == 0) ? 0 : part[t - 1];
  for (int i = lo; i < hi; ++i) {
    startA[i] = base; cursor[i] = base; base += deg[i];
  }
  if (t == 1023) startA[NN] = base;
}

__global__ void k_scatter(const int* __restrict__ row, int* __restrict__ cursor,
                          int* __restrict__ eperm) {
  int e = blockIdx.x * 256 + threadIdx.x;
  if (e < NE) {
    int p = atomicAdd(cursor + row[e], 1);
    eperm[p] = e;
  }
}

// ---------------- q = h@Wq + bq (permuted bf16 out) + hb (bf16 h copy) -----
// qg2[node*64 + m16*4 + nt] = q[col = m16 + 16*nt]
__global__ __launch_bounds__(256)
void k_q(const float* __restrict__ h, const unsigned* __restrict__ Wqp,
         const float* __restrict__ bq, unsigned short* __restrict__ qg2,
         unsigned short* __restrict__ hb) {
  __shared__ unsigned sWqp[32 * 64];
  __shared__ float sHr[4][64];
  const int tid = threadIdx.x;
  for (int idx = tid; idx < 2048; idx += 256) sWqp[idx] = Wqp[idx];
  __syncthreads();
  const int wv = tid >> 6, lane = tid & 63;
  const int node = blockIdx.x * 4 + wv;
  float hv = h[node * 64 + lane];
  sHr[wv][lane] = hv;
  hb[(size_t)node * 64 + lane] = bf16_of(hv);
  float q = bq[lane];
  const float2* hp = (const float2*)sHr[wv];
#pragma unroll 8
  for (int i2 = 0; i2 < 32; ++i2) {
    unsigned w = sWqp[i2 * 64 + lane];
    float2 hbv = hp[i2];
    q += hbv.x * blo(w) + hbv.y * bhi(w);
  }
  qg2[(size_t)node * 64 + (lane & 15) * 4 + (lane >> 4)] = bf16_of(q);
}

// ---------------- main fused kernel: 64 CSR slots per block ----------------
__global__ __launch_bounds__(256, 3)
void k_kv(const unsigned short* __restrict__ hb, const float* __restrict__ coord,
          const int* __restrict__ row, const int* __restrict__ col,
          const float* __restrict__ edge_attr, const float* __restrict__ bkv,
          const float* __restrict__ b1, const float* __restrict__ W2,
          const float* __restrict__ rnorm, const int* __restrict__ eperm,
          const unsigned short* __restrict__ Bkvb,
          const unsigned short* __restrict__ W1tb,
          const unsigned short* __restrict__ qg2,
          float* __restrict__ exg, float* __restrict__ l_g,
          float* __restrict__ hacc_g, float* __restrict__ cacc_g) {
  __shared__ __align__(16) unsigned short sA[64][104];   // feat bf16; later v
  __shared__ __align__(16) unsigned char uReg[26624];    // sB, later S/T
  __shared__ __align__(16) unsigned short sW1t[64][88];  // W1^T bf16
  __shared__ unsigned short cdb[64][12];                 // coord_diff bf16
  __shared__ int sCol[64], sRow[64], sE[64];
  __shared__ float exb[64];
  __shared__ int segStart[65];
  __shared__ int segCnt;

  unsigned short (*sB)[104] = (unsigned short(*)[104])uReg;
  float* S = (float*)uReg;                   // [64][68] ex*v
  float* T = (float*)(uReg + 64 * 68 * 4);   // [64][12] ex*trans

  const int tid = threadIdx.x;
  const int base = blockIdx.x * 64;

  if (tid < 64) {
    int e = eperm[base + tid];
    sE[tid] = e; sCol[tid] = col[e]; sRow[tid] = row[e];
    // segment boundaries (CSR order -> sRow non-decreasing)
    bool isStart = (tid == 0) || (sRow[tid] != sRow[tid - 1]);
    unsigned long long mask = __ballot(isStart);
    int k = __popcll(mask & ((1ull << tid) - 1ull));
    if (isStart) segStart[k] = tid;
    if (tid == 0) {
      int cnt = __popcll(mask);
      segCnt = cnt;
      segStart[cnt] = 64;
    }
  }
  // weights: pure vector copies (L2-hot)
  {
    const uint4* gb = (const uint4*)Bkvb;
    uint4* sb = (uint4*)&sB[0][0];
    for (int idx = tid; idx < 1664; idx += 256) sb[idx] = gb[idx];
    const uint4* gw = (const uint4*)W1tb;
    uint4* sw = (uint4*)&sW1t[0][0];
    for (int idx = tid; idx < 704; idx += 256) sw[idx] = gw[idx];
  }
  __syncthreads();   // sCol/sRow/sE/seg visible

  // h[col] gather from bf16 copy: 64 rows x 8 uint4
  for (int idx = tid; idx < 512; idx += 256) {
    int s = idx >> 3, q8 = idx & 7;
    uint4 u = ((const uint4*)(hb + (size_t)sCol[s] * 64))[q8];
    *(uint4*)&sA[s][16 + q8 * 8] = u;
  }
  // edge_attr: 64 rows x 8 dword-cols (pairwise pack)
  for (int idx = tid; idx < 512; idx += 256) {
    int s = idx >> 3, c2 = idx & 7;
    float2 ea = ((const float2*)(edge_attr + (size_t)sE[s] * 16))[c2];
    *(unsigned*)&sA[s][80 + 2 * c2] = pack_bf(ea.x, ea.y);
  }
  // radial + cdb via register shuffles
  {
    const int wv = tid >> 6, lane = tid & 63;
    const int grp = lane >> 4, g = lane & 15;
    const int c4 = g >> 2, f4 = g & 3;
    const float rn = rnorm[g];
#pragma unroll
    for (int it = 0; it < 4; ++it) {
      int slot = 16 * wv + it * 4 + grp;
      int r = sRow[slot], c = sCol[slot];
      float cd = 0.f;
      if (g < 12) cd = coord[r * 12 + g] - coord[c * 12 + g];
      float rad = 0.f;
#pragma unroll
      for (int d = 0; d < 3; ++d)
        rad += __shfl(cd, grp * 16 + c4 * 3 + d) * __shfl(cd, grp * 16 + f4 * 3 + d);
      sA[slot][g] = bf16_of(rad * rn);
      if (g < 12) cdb[slot][g] = bf16_of(cd);
    }
  }
  __syncthreads();   // sA complete

  const int wv = tid >> 6, lane = tid & 63;
  const int m16 = lane & 15, quad = lane >> 4;
  const int arow = 16 * wv + m16;

  // kv = feat @ [Wk|Wv]
  floatx4 acc[8];
#pragma unroll
  for (int i = 0; i < 8; ++i) acc[i] = (floatx4){0.f, 0.f, 0.f, 0.f};
#pragma unroll
  for (int ks = 0; ks < 3; ++ks) {
    short8 af = *(const short8*)&sA[arow][ks * 32 + quad * 8];
#pragma unroll
    for (int nt = 0; nt < 8; ++nt) {
      short8 bf = *(const short8*)&sB[nt * 16 + m16][ks * 32 + quad * 8];
      acc[nt] = __builtin_amdgcn_mfma_f32_16x16x32_bf16(af, bf, acc[nt], 0, 0, 0);
    }
  }
#pragma unroll
  for (int nt = 0; nt < 4; ++nt) {
    float bk = bkv[2 * (m16 + 16 * nt)];
    float bv = bkv[2 * (m16 + 16 * nt) + 1];
#pragma unroll
    for (int r = 0; r < 4; ++r) { acc[nt][r] += bk; acc[nt + 4][r] += bv; }
  }
  // alpha = q . k  -> ex = exp(alpha)  (no max stabilizer: |alpha| << 88)
  float part[4] = {0.f, 0.f, 0.f, 0.f};
#pragma unroll
  for (int r = 0; r < 4; ++r) {
    int nrow = sRow[16 * wv + quad * 4 + r];
    uint2 qp = *(const uint2*)(qg2 + (size_t)nrow * 64 + m16 * 4);
    part[r] += blo(qp.x) * acc[0][r] + bhi(qp.x) * acc[1][r] +
               blo(qp.y) * acc[2][r] + bhi(qp.y) * acc[3][r];
  }
#pragma unroll
  for (int off = 1; off < 16; off <<= 1) {
#pragma unroll
    for (int r = 0; r < 4; ++r) part[r] += __shfl_xor(part[r], off);
  }
  float ex[4];
#pragma unroll
  for (int r = 0; r < 4; ++r) ex[r] = __expf(part[r]);
  if (m16 == 0) {
#pragma unroll
    for (int r = 0; r < 4; ++r) {
      exg[base + 16 * wv + quad * 4 + r] = ex[r];
      exb[16 * wv + quad * 4 + r] = ex[r];
    }
  }

  __syncthreads();   // all kv-MFMA sB reads done; S/T may now overwrite uReg

  // v (bf16) -> sA rows (wave-private) for W1 GEMM; ex*v (fp32) -> S
#pragma unroll
  for (int nt = 0; nt < 4; ++nt)
#pragma unroll
    for (int r = 0; r < 4; ++r) {
      int slot = 16 * wv + quad * 4 + r;
      sA[slot][m16 + 16 * nt] = bf16_of(acc[4 + nt][r]);
      S[slot * 68 + m16 + 16 * nt] = ex[r] * acc[4 + nt][r];
    }
  // t = silu(v @ W1 + b1)
  floatx4 tacc[4];
#pragma unroll
  for (int i = 0; i < 4; ++i) tacc[i] = (floatx4){0.f, 0.f, 0.f, 0.f};
#pragma unroll
  for (int ks = 0; ks < 2; ++ks) {
    short8 af = *(const short8*)&sA[arow][ks * 32 + quad * 8];
#pragma unroll
    for (int nt = 0; nt < 4; ++nt) {
      short8 bf = *(const short8*)&sW1t[nt * 16 + m16][ks * 32 + quad * 8];
      tacc[nt] = __builtin_amdgcn_mfma_f32_16x16x32_bf16(af, bf, tacc[nt], 0, 0, 0);
    }
  }
#pragma unroll
  for (int nt = 0; nt < 4; ++nt) {
    float bb = b1[m16 + 16 * nt];
#pragma unroll
    for (int r = 0; r < 4; ++r) {
      float t = tacc[nt][r] + bb;
      tacc[nt][r] = t / (1.f + __expf(-t));
    }
  }
  // cv = t @ W2 (all-reduce over the 16-lane group)
  float cvp[4][4];
#pragma unroll
  for (int r = 0; r < 4; ++r)
#pragma unroll
    for (int c = 0; c < 4; ++c) cvp[r][c] = 0.f;
#pragma unroll
  for (int nt = 0; nt < 4; ++nt) {
    float4 w2r = ((const float4*)W2)[m16 + 16 * nt];
#pragma unroll
    for (int r = 0; r < 4; ++r) {
      cvp[r][0] += tacc[nt][r] * w2r.x;
      cvp[r][1] += tacc[nt][r] * w2r.y;
      cvp[r][2] += tacc[nt][r] * w2r.z;
      cvp[r][3] += tacc[nt][r] * w2r.w;
    }
  }
#pragma unroll
  for (int off = 1; off < 16; off <<= 1) {
#pragma unroll
    for (int r = 0; r < 4; ++r)
#pragma unroll
      for (int c = 0; c < 4; ++c) cvp[r][c] += __shfl_xor(cvp[r][c], off);
  }
  // T = ex * cd * cv
  if (m16 < 12) {
#pragma unroll
    for (int r = 0; r < 4; ++r) {
      int slot = 16 * wv + quad * 4 + r;
      float cvv = (m16 < 3) ? cvp[r][0] : (m16 < 6) ? cvp[r][1]
                : (m16 < 9) ? cvp[r][2] : cvp[r][3];
      T[slot * 12 + m16] = ex[r] * bf2f(cdb[slot][m16]) * cvv;
    }
  }
  __syncthreads();   // S/T/exb complete

  // per-node partial reduction + atomic accumulate
  const int nseg = segCnt;
  for (int k = wv; k < nseg; k += 4) {
    int lo = segStart[k], hi = segStart[k + 1];
    int n = sRow[lo];
    float hs = 0.f, ls = 0.f, cs = 0.f;
    for (int s = lo; s < hi; ++s) {
      hs += S[s * 68 + lane];
      ls += exb[s];
      if (lane < 12) cs += T[s * 12 + lane];
    }
    atomicAdd(hacc_g + (size_t)n * 64 + lane, hs);
    if (lane == 0) atomicAdd(l_g + n, ls);
    if (lane < 12) atomicAdd(cacc_g + (size_t)n * 12 + lane, cs);
  }
}

// ---------------- finalize ----------------
__global__ __launch_bounds__(256)
void k_fin(const float* __restrict__ h, const float* __restrict__ coord,
           const int* __restrict__ startA, const int* __restrict__ eperm,
           const float* __restrict__ exg, const float* __restrict__ l_g,
           const float* __restrict__ hacc_g, const float* __restrict__ cacc_g,
           float* __restrict__ out) {
  const int wv = threadIdx.x >> 6, lane = threadIdx.x & 63;
  const int node = blockIdx.x * 4 + wv;
  float l = l_g[node];
  float inv = (l > 0.f) ? 1.f / l : 0.f;
  out[node * 64 + lane] = h[node * 64 + lane] + hacc_g[(size_t)node * 64 + lane] * inv;
  if (lane < 12)
    out[NN * 64 + node * 12 + lane] =
        coord[node * 12 + lane] + cacc_g[(size_t)node * 12 + lane] * inv;
  const int s0 = startA[node], s1 = startA[node + 1];
  for (int j = s0 + lane; j < s1; j += 64)
    out[NN * 64 + NN * 12 + eperm[j]] = exg[j] * inv;
}

extern "C" void kernel_launch(void* const* d_in, const int* in_sizes, int n_in,
                              void* d_out, int out_size, void* d_ws, size_t ws_size,
                              hipStream_t stream) {
  const float* h         = (const float*)d_in[0];
  const float* coord     = (const float*)d_in[1];
  const int*   row       = (const int*)d_in[2];
  const int*   col       = (const int*)d_in[3];
  const float* edge_attr = (const float*)d_in[4];
  const float* Wq        = (const float*)d_in[5];
  const float* bq        = (const float*)d_in[6];
  const float* Wkv       = (const float*)d_in[7];
  const float* bkv       = (const float*)d_in[8];
  const float* W1        = (const float*)d_in[9];
  const float* b1        = (const float*)d_in[10];
  const float* W2        = (const float*)d_in[11];
  float* out = (float*)d_out;

  size_t off = 0;
  char* wsb = (char*)d_ws;
  auto alloc = [&](size_t bytes) {
    off = (off + 255) & ~(size_t)255;
    void* p = wsb + off; off += bytes; return p;
  };
  // ---- zeroed region (contiguous, one memset) ----
  float*          norm_acc = (float*)alloc(16 * 4);
  int*            deg      = (int*)alloc((size_t)NN * 4);
  float*          l_g      = (float*)alloc((size_t)NN * 4);
  float*          hacc_g   = (float*)alloc((size_t)NN * 64 * 4);
  float*          cacc_g   = (float*)alloc((size_t)NN * 12 * 4);
  size_t zbytes = off;
  // ---- rest ----
  float*          rnorm    = (float*)alloc(16 * 4);
  int*            startA   = (int*)alloc(((size_t)NN + 1) * 4);
  int*            cursor   = (int*)alloc((size_t)NN * 4);
  int*            eperm    = (int*)alloc((size_t)NE * 4);
  float*          exg      = (float*)alloc((size_t)NE * 4);
  unsigned short* qg2      = (unsigned short*)alloc((size_t)NN * 64 * 2);
  unsigned short* hb       = (unsigned short*)alloc((size_t)NN * 64 * 2);
  unsigned short* Bkvb     = (unsigned short*)alloc(128 * 104 * 2);
  unsigned short* W1tb     = (unsigned short*)alloc(64 * 88 * 2);
  unsigned*       Wqp      = (unsigned*)alloc(32 * 64 * 4);

  hipMemsetAsync(d_ws, 0, zbytes, stream);

  k_radnorm<<<1024, 256, 0, stream>>>(coord, row, col, norm_acc, deg);
  k_prep<<<32, 256, 0, stream>>>(Wkv, W1, Wq, Bkvb, W1tb, Wqp);
  k_scan<<<1, 1024, 0, stream>>>(deg, startA, cursor, norm_acc, rnorm);
  k_scatter<<<(NE + 255) / 256, 256, 0, stream>>>(row, cursor, eperm);
  k_q<<<NN / 4, 256, 0, stream>>>(h, Wqp, bq, qg2, hb);
  k_kv<<<NE / 64, 256, 0, stream>>>(hb, coord, row, col, edge_attr, bkv, b1, W2,
                                    rnorm, eperm, Bkvb, W1tb, qg2,
                                    exg, l_g, hacc_g, cacc_g);
  k_fin<<<NN / 4, 256, 0, stream>>>(h, coord, startA, eperm, exg, l_g,
                                    hacc_g, cacc_g, out);
}

// Round 6
// 658.266 us; speedup vs baseline: 1.0799x; 1.0799x over previous
//
#include <hip/hip_runtime.h>
#include <math.h>

#define NN 50000
#define NE 800000

typedef __attribute__((ext_vector_type(8))) short short8;
typedef __attribute__((ext_vector_type(4))) float floatx4;

__device__ __forceinline__ unsigned short bf16_of(float x) {
  unsigned u = __float_as_uint(x);
  u += 0x7fffu + ((u >> 16) & 1u);
  return (unsigned short)(u >> 16);
}
__device__ __forceinline__ float bf2f(unsigned short u) {
  return __uint_as_float(((unsigned)u) << 16);
}
__device__ __forceinline__ unsigned pack_bf(float a, float b) {
  unsigned ua = __float_as_uint(a); ua += 0x7fffu + ((ua >> 16) & 1u);
  unsigned ub = __float_as_uint(b); ub += 0x7fffu + ((ub >> 16) & 1u);
  return (ua >> 16) | (ub & 0xffff0000u);
}
__device__ __forceinline__ float blo(unsigned w) { return __uint_as_float(w << 16); }
__device__ __forceinline__ float bhi(unsigned w) { return __uint_as_float(w & 0xffff0000u); }

// ---------------- norm over all edges + degree count ----------------
__global__ __launch_bounds__(256)
void k_radnorm(const float* __restrict__ coord, const int* __restrict__ row,
               const int* __restrict__ col, float* __restrict__ norm_acc,
               int* __restrict__ deg) {
  const int lane = threadIdx.x & 63;
  const int cf = lane & 15;
  const int eg = lane >> 4;
  const int c4 = cf >> 2, f4 = cf & 3;
  const int wid = blockIdx.x * (blockDim.x >> 6) + (threadIdx.x >> 6);
  const int nw = gridDim.x * (blockDim.x >> 6);
  float acc = 0.f;
  for (int base = wid * 4; base < NE; base += nw * 4) {
    int e = base + eg;
    int r = row[e], c = col[e];
    const float* cr = coord + r * 12;
    const float* cc = coord + c * 12;
    float rad = 0.f;
#pragma unroll
    for (int d = 0; d < 3; ++d) {
      float a = cr[c4 * 3 + d] - cc[c4 * 3 + d];
      float b = cr[f4 * 3 + d] - cc[f4 * 3 + d];
      rad += a * b;
    }
    acc += rad * rad;
    if (cf == 0) atomicAdd(deg + r, 1);
  }
  acc += __shfl_xor(acc, 16);
  acc += __shfl_xor(acc, 32);
  if (lane < 16) atomicAdd(norm_acc + cf, acc);
}

// ---------------- weight pre-conversion (once) ----------------
__global__ __launch_bounds__(256)
void k_prep(const float* __restrict__ Wkv, const float* __restrict__ W1,
            const float* __restrict__ Wq, unsigned short* __restrict__ Bkvb,
            unsigned short* __restrict__ W1tb, unsigned* __restrict__ Wqp) {
  const int gid = blockIdx.x * 256 + threadIdx.x;
  const int np = gridDim.x * 256;
  for (int idx = gid; idx < 128 * 96; idx += np) {
    int n = idx & 127, kk = idx >> 7;
    float w = (n < 64) ? Wkv[kk * 128 + 2 * n] : Wkv[kk * 128 + 2 * (n - 64) + 1];
    Bkvb[n * 104 + kk] = bf16_of(w);
  }
  for (int idx = gid; idx < 64 * 64; idx += np) {
    int n = idx & 63, kk = idx >> 6;
    W1tb[n * 88 + kk] = bf16_of(W1[kk * 64 + n]);
  }
  for (int idx = gid; idx < 32 * 64; idx += np) {
    int i2 = idx >> 6, j = idx & 63;
    Wqp[idx] = pack_bf(Wq[(2 * i2) * 64 + j], Wq[(2 * i2 + 1) * 64 + j]);
  }
}

// ---------------- CSR scan (+ rnorm finalize folded in) ----------------
__global__ void k_scan(const int* __restrict__ deg, int* __restrict__ startA,
                       int* __restrict__ cursor, const float* __restrict__ norm_acc,
                       float* __restrict__ rnorm) {
  __shared__ int part[1024];
  const int t = threadIdx.x;
  if (t < 16) rnorm[t] = 1.0f / fmaxf(sqrtf(norm_acc[t]), 1e-12f);
  const int CH = (NN + 1023) / 1024;
  const int lo = t * CH, hi = (lo + CH < NN) ? lo + CH : NN;
  int s = 0;
  for (int i = lo; i < hi; ++i) s += deg[i];
  part[t] = s;
  __syncthreads();
  for (int off = 1; off < 1024; off <<= 1) {
    int v = (t >= off) ? part[t - off] : 0;
    __syncthreads();
    part[t] += v;
    __syncthreads();
  }
  int base = (t == 0) ? 0 : part[t - 1];
  for (int i = lo; i < hi; ++i) {
    startA[i] = base; cursor[i] = base; base += deg[i];
  }
  if (t == 1023) startA[NN] = base;
}

__global__ void k_scatter(const int* __restrict__ row, int* __restrict__ cursor,
                          int* __restrict__ eperm) {
  int e = blockIdx.x * 256 + threadIdx.x;
  if (e < NE) {
    int p = atomicAdd(cursor + row[e], 1);
    eperm[p] = e;
  }
}

// ---------------- q = h@Wq + bq (permuted bf16 out) + hb (bf16 h copy) -----
// qg2[node*64 + m16*4 + nt] = q[col = m16 + 16*nt]
__global__ __launch_bounds__(256)
void k_q(const float* __restrict__ h, const unsigned* __restrict__ Wqp,
         const float* __restrict__ bq, unsigned short* __restrict__ qg2,
         unsigned short* __restrict__ hb) {
  __shared__ unsigned sWqp[32 * 64];
  __shared__ float sHr[4][64];
  const int tid = threadIdx.x;
  for (int idx = tid; idx < 2048; idx += 256) sWqp[idx] = Wqp[idx];
  __syncthreads();
  const int wv = tid >> 6, lane = tid & 63;
  const int node = blockIdx.x * 4 + wv;
  float hv = h[node * 64 + lane];
  sHr[wv][lane] = hv;
  hb[(size_t)node * 64 + lane] = bf16_of(hv);
  float q = bq[lane];
  const float2* hp = (const float2*)sHr[wv];
#pragma unroll 8
  for (int i2 = 0; i2 < 32; ++i2) {
    unsigned w = sWqp[i2 * 64 + lane];
    float2 hbv = hp[i2];
    q += hbv.x * blo(w) + hbv.y * bhi(w);
  }
  qg2[(size_t)node * 64 + (lane & 15) * 4 + (lane >> 4)] = bf16_of(q);
}

// ---------------- main MFMA GEMM over 64 CSR slots per block ----------------
__global__ __launch_bounds__(256, 3)
void k_kv(const unsigned short* __restrict__ hb, const float* __restrict__ coord,
          const int* __restrict__ row, const int* __restrict__ col,
          const float* __restrict__ edge_attr, const float* __restrict__ bkv,
          const float* __restrict__ b1, const float* __restrict__ W2,
          const float* __restrict__ rnorm, const int* __restrict__ eperm,
          const unsigned short* __restrict__ Bkvb,
          const unsigned short* __restrict__ W1tb,
          const unsigned short* __restrict__ qg2,
          float* __restrict__ exg, unsigned short* __restrict__ vg,
          unsigned short* __restrict__ transg) {
  __shared__ __align__(16) unsigned short sA[64][104];   // feat bf16; later v
  __shared__ __align__(16) unsigned short sB[128][104];  // [k|v]^T bf16
  __shared__ __align__(16) unsigned short sW1t[64][88];  // W1^T bf16
  __shared__ unsigned short cdb[64][12];                 // coord_diff bf16
  __shared__ int sCol[64], sRow[64], sE[64];

  const int tid = threadIdx.x;
  const int base = blockIdx.x * 64;

  if (tid < 64) {
    int e = eperm[base + tid];
    sE[tid] = e; sCol[tid] = col[e]; sRow[tid] = row[e];
  }
  // weights: pure vector copies (L2-hot)
  {
    const uint4* gb = (const uint4*)Bkvb;
    uint4* sb = (uint4*)&sB[0][0];
    for (int idx = tid; idx < 1664; idx += 256) sb[idx] = gb[idx];
    const uint4* gw = (const uint4*)W1tb;
    uint4* sw = (uint4*)&sW1t[0][0];
    for (int idx = tid; idx < 704; idx += 256) sw[idx] = gw[idx];
  }
  __syncthreads();   // sCol/sRow/sE visible

  // h[col] gather from bf16 copy: 64 rows x 8 uint4 (128B/row)
  for (int idx = tid; idx < 512; idx += 256) {
    int s = idx >> 3, q8 = idx & 7;
    uint4 u = ((const uint4*)(hb + (size_t)sCol[s] * 64))[q8];
    *(uint4*)&sA[s][16 + q8 * 8] = u;
  }
  // edge_attr: 64 rows x 8 dword-cols (pairwise pack)
  for (int idx = tid; idx < 512; idx += 256) {
    int s = idx >> 3, c2 = idx & 7;
    float2 ea = ((const float2*)(edge_attr + (size_t)sE[s] * 16))[c2];
    *(unsigned*)&sA[s][80 + 2 * c2] = pack_bf(ea.x, ea.y);
  }
  // radial + cdb via register shuffles
  {
    const int wv = tid >> 6, lane = tid & 63;
    const int grp = lane >> 4, g = lane & 15;
    const int c4 = g >> 2, f4 = g & 3;
    const float rn = rnorm[g];
#pragma unroll
    for (int it = 0; it < 4; ++it) {
      int slot = 16 * wv + it * 4 + grp;
      int r = sRow[slot], c = sCol[slot];
      float cd = 0.f;
      if (g < 12) cd = coord[r * 12 + g] - coord[c * 12 + g];
      float rad = 0.f;
#pragma unroll
      for (int d = 0; d < 3; ++d)
        rad += __shfl(cd, grp * 16 + c4 * 3 + d) * __shfl(cd, grp * 16 + f4 * 3 + d);
      sA[slot][g] = bf16_of(rad * rn);
      if (g < 12) cdb[slot][g] = bf16_of(cd);
    }
  }
  __syncthreads();   // sA complete

  const int wv = tid >> 6, lane = tid & 63;
  const int m16 = lane & 15, quad = lane >> 4;
  const int arow = 16 * wv + m16;

  // kv = feat @ [Wk|Wv]
  floatx4 acc[8];
#pragma unroll
  for (int i = 0; i < 8; ++i) acc[i] = (floatx4){0.f, 0.f, 0.f, 0.f};
#pragma unroll
  for (int ks = 0; ks < 3; ++ks) {
    short8 af = *(const short8*)&sA[arow][ks * 32 + quad * 8];
#pragma unroll
    for (int nt = 0; nt < 8; ++nt) {
      short8 bf = *(const short8*)&sB[nt * 16 + m16][ks * 32 + quad * 8];
      acc[nt] = __builtin_amdgcn_mfma_f32_16x16x32_bf16(af, bf, acc[nt], 0, 0, 0);
    }
  }
#pragma unroll
  for (int nt = 0; nt < 4; ++nt) {
    float bk = bkv[2 * (m16 + 16 * nt)];
    float bv = bkv[2 * (m16 + 16 * nt) + 1];
#pragma unroll
    for (int r = 0; r < 4; ++r) { acc[nt][r] += bk; acc[nt + 4][r] += bv; }
  }
  // alpha = q . k -> ex = exp(alpha)   (no max stabilizer: |alpha| << 88)
  float part[4] = {0.f, 0.f, 0.f, 0.f};
#pragma unroll
  for (int r = 0; r < 4; ++r) {
    int nrow = sRow[16 * wv + quad * 4 + r];
    uint2 qp = *(const uint2*)(qg2 + (size_t)nrow * 64 + m16 * 4);
    part[r] += blo(qp.x) * acc[0][r] + bhi(qp.x) * acc[1][r] +
               blo(qp.y) * acc[2][r] + bhi(qp.y) * acc[3][r];
  }
#pragma unroll
  for (int off = 1; off < 16; off <<= 1) {
#pragma unroll
    for (int r = 0; r < 4; ++r) part[r] += __shfl_xor(part[r], off);
  }
  if (m16 == 0) {
#pragma unroll
    for (int r = 0; r < 4; ++r)
      exg[base + 16 * wv + quad * 4 + r] = __expf(part[r]);
  }
  // v -> sA rows (wave-private), then linear global write
#pragma unroll
  for (int nt = 0; nt < 4; ++nt)
#pragma unroll
    for (int r = 0; r < 4; ++r)
      sA[16 * wv + quad * 4 + r][m16 + 16 * nt] = bf16_of(acc[4 + nt][r]);
  for (int i = lane; i < 16 * 32; i += 64) {
    int r = i >> 5, dw = i & 31;
    unsigned u = *(const unsigned*)&sA[16 * wv + r][dw * 2];
    ((unsigned*)vg)[(size_t)(base + 16 * wv + r) * 32 + dw] = u;
  }
  // t = silu(v @ W1 + b1)
  floatx4 tacc[4];
#pragma unroll
  for (int i = 0; i < 4; ++i) tacc[i] = (floatx4){0.f, 0.f, 0.f, 0.f};
#pragma unroll
  for (int ks = 0; ks < 2; ++ks) {
    short8 af = *(const short8*)&sA[arow][ks * 32 + quad * 8];
#pragma unroll
    for (int nt = 0; nt < 4; ++nt) {
      short8 bf = *(const short8*)&sW1t[nt * 16 + m16][ks * 32 + quad * 8];
      tacc[nt] = __builtin_amdgcn_mfma_f32_16x16x32_bf16(af, bf, tacc[nt], 0, 0, 0);
    }
  }
#pragma unroll
  for (int nt = 0; nt < 4; ++nt) {
    float bb = b1[m16 + 16 * nt];
#pragma unroll
    for (int r = 0; r < 4; ++r) {
      float t = tacc[nt][r] + bb;
      tacc[nt][r] = t / (1.f + __expf(-t));
    }
  }
  // cv = t @ W2 (all-reduce across the 16-lane group)
  float cvp[4][4];
#pragma unroll
  for (int r = 0; r < 4; ++r)
#pragma unroll
    for (int c = 0; c < 4; ++c) cvp[r][c] = 0.f;
#pragma unroll
  for (int nt = 0; nt < 4; ++nt) {
    float4 w2r = ((const float4*)W2)[m16 + 16 * nt];
#pragma unroll
    for (int r = 0; r < 4; ++r) {
      cvp[r][0] += tacc[nt][r] * w2r.x;
      cvp[r][1] += tacc[nt][r] * w2r.y;
      cvp[r][2] += tacc[nt][r] * w2r.z;
      cvp[r][3] += tacc[nt][r] * w2r.w;
    }
  }
#pragma unroll
  for (int off = 1; off < 16; off <<= 1) {
#pragma unroll
    for (int r = 0; r < 4; ++r)
#pragma unroll
      for (int c = 0; c < 4; ++c) cvp[r][c] += __shfl_xor(cvp[r][c], off);
  }
  // trans = cd * cv  (bf16)
#pragma unroll
  for (int r = 0; r < 4; ++r) {
    int row16 = quad * 4 + r;
    if (m16 < 12) {
      float cvv = (m16 < 3) ? cvp[r][0] : (m16 < 6) ? cvp[r][1]
                : (m16 < 9) ? cvp[r][2] : cvp[r][3];
      float cdv = bf2f(cdb[16 * wv + row16][m16]);
      transg[(size_t)(base + 16 * wv + row16) * 12 + m16] = bf16_of(cdv * cvv);
    }
  }
}

// ---------------- per-node accumulate (single streaming pass) --------------
__global__ __launch_bounds__(256)
void k_accum(const float* __restrict__ h, const float* __restrict__ coord,
             const int* __restrict__ startA, const int* __restrict__ eperm,
             const float* __restrict__ exg,
             const unsigned short* __restrict__ vg,
             const unsigned short* __restrict__ transg,
             float* __restrict__ out) {
  const int wv = threadIdx.x >> 6, lane = threadIdx.x & 63;
  const int node = blockIdx.x * 4 + wv;
  const int s0 = startA[node], s1 = startA[node + 1];

  float l = 0.f, h0 = 0.f, h1 = 0.f, c0 = 0.f, c1 = 0.f;
  int j = s0;
  for (; j + 1 < s1; j += 2) {
    float e0 = exg[j], e1 = exg[j + 1];
    float va = bf2f(vg[(size_t)j * 64 + lane]);
    float vb = bf2f(vg[(size_t)(j + 1) * 64 + lane]);
    float ta = (lane < 12) ? bf2f(transg[(size_t)j * 12 + lane]) : 0.f;
    float tb = (lane < 12) ? bf2f(transg[(size_t)(j + 1) * 12 + lane]) : 0.f;
    l += e0 + e1;
    h0 += e0 * va; h1 += e1 * vb;
    c0 += e0 * ta; c1 += e1 * tb;
  }
  if (j < s1) {
    float e0 = exg[j];
    float va = bf2f(vg[(size_t)j * 64 + lane]);
    float ta = (lane < 12) ? bf2f(transg[(size_t)j * 12 + lane]) : 0.f;
    l += e0; h0 += e0 * va; c0 += e0 * ta;
  }
  float hacc = h0 + h1, cacc = c0 + c1;
  const float inv = (l > 0.f) ? 1.f / l : 0.f;
  out[node * 64 + lane] = h[node * 64 + lane] + hacc * inv;
  if (lane < 12)
    out[NN * 64 + node * 12 + lane] = coord[node * 12 + lane] + cacc * inv;
  for (int j2 = s0 + lane; j2 < s1; j2 += 64)
    out[NN * 64 + NN * 12 + eperm[j2]] = exg[j2] * inv;
}

extern "C" void kernel_launch(void* const* d_in, const int* in_sizes, int n_in,
                              void* d_out, int out_size, void* d_ws, size_t ws_size,
                              hipStream_t stream) {
  const float* h         = (const float*)d_in[0];
  const float* coord     = (const float*)d_in[1];
  const int*   row       = (const int*)d_in[2];
  const int*   col       = (const int*)d_in[3];
  const float* edge_attr = (const float*)d_in[4];
  const float* Wq        = (const float*)d_in[5];
  const float* bq        = (const float*)d_in[6];
  const float* Wkv       = (const float*)d_in[7];
  const float* bkv       = (const float*)d_in[8];
  const float* W1        = (const float*)d_in[9];
  const float* b1        = (const float*)d_in[10];
  const float* W2        = (const float*)d_in[11];
  float* out = (float*)d_out;

  size_t off = 0;
  char* wsb = (char*)d_ws;
  auto alloc = [&](size_t bytes) {
    off = (off + 255) & ~(size_t)255;
    void* p = wsb + off; off += bytes; return p;
  };
  // ---- zeroed region (contiguous, one memset) ----
  float*          norm_acc = (float*)alloc(16 * 4);
  int*            deg      = (int*)alloc((size_t)NN * 4);
  size_t zbytes = off;
  // ---- rest ----
  float*          rnorm    = (float*)alloc(16 * 4);
  int*            startA   = (int*)alloc(((size_t)NN + 1) * 4);
  int*            cursor   = (int*)alloc((size_t)NN * 4);
  int*            eperm    = (int*)alloc((size_t)NE * 4);
  float*          exg      = (float*)alloc((size_t)NE * 4);
  unsigned short* qg2      = (unsigned short*)alloc((size_t)NN * 64 * 2);
  unsigned short* hb       = (unsigned short*)alloc((size_t)NN * 64 * 2);
  unsigned short* Bkvb     = (unsigned short*)alloc(128 * 104 * 2);
  unsigned short* W1tb     = (unsigned short*)alloc(64 * 88 * 2);
  unsigned*       Wqp      = (unsigned*)alloc(32 * 64 * 4);
  unsigned short* transg   = (unsigned short*)alloc((size_t)NE * 12 * 2);
  unsigned short* vg       = (unsigned short*)alloc((size_t)NE * 64 * 2);

  hipMemsetAsync(d_ws, 0, zbytes, stream);

  k_radnorm<<<1024, 256, 0, stream>>>(coord, row, col, norm_acc, deg);
  k_prep<<<32, 256, 0, stream>>>(Wkv, W1, Wq, Bkvb, W1tb, Wqp);
  k_scan<<<1, 1024, 0, stream>>>(deg, startA, cursor, norm_acc, rnorm);
  k_scatter<<<(NE + 255) / 256, 256, 0, stream>>>(row, cursor, eperm);
  k_q<<<NN / 4, 256, 0, stream>>>(h, Wqp, bq, qg2, hb);
  k_kv<<<NE / 64, 256, 0, stream>>>(hb, coord, row, col, edge_attr, bkv, b1, W2,
                                    rnorm, eperm, Bkvb, W1tb, qg2,
                                    exg, vg, transg);
  k_accum<<<NN / 4, 256, 0, stream>>>(h, coord, startA, eperm, exg, vg,
                                      transg, out);
}

// Round 7
// 636.694 us; speedup vs baseline: 1.1164x; 1.0339x over previous
//
#include <hip/hip_runtime.h>
#include <math.h>

#define NN 50000
#define NE 800000

typedef __attribute__((ext_vector_type(8))) short short8;
typedef __attribute__((ext_vector_type(4))) float floatx4;

__device__ __forceinline__ unsigned short bf16_of(float x) {
  unsigned u = __float_as_uint(x);
  u += 0x7fffu + ((u >> 16) & 1u);
  return (unsigned short)(u >> 16);
}
__device__ __forceinline__ float bf2f(unsigned short u) {
  return __uint_as_float(((unsigned)u) << 16);
}
__device__ __forceinline__ unsigned pack_bf(float a, float b) {
  unsigned ua = __float_as_uint(a); ua += 0x7fffu + ((ua >> 16) & 1u);
  unsigned ub = __float_as_uint(b); ub += 0x7fffu + ((ub >> 16) & 1u);
  return (ua >> 16) | (ub & 0xffff0000u);
}
__device__ __forceinline__ float blo(unsigned w) { return __uint_as_float(w << 16); }
__device__ __forceinline__ float bhi(unsigned w) { return __uint_as_float(w & 0xffff0000u); }

// ---------- k_pre: weight conversion + radial-norm + degree count ----------
__global__ __launch_bounds__(256)
void k_pre(const float* __restrict__ coord, const int* __restrict__ row,
           const int* __restrict__ col, const float* __restrict__ Wkv,
           const float* __restrict__ W1, const float* __restrict__ Wq,
           float* __restrict__ norm_acc, int* __restrict__ deg,
           unsigned short* __restrict__ Bkvb, unsigned short* __restrict__ W1tb,
           unsigned* __restrict__ Wqp) {
  const int gid = blockIdx.x * 256 + threadIdx.x;
  const int np = gridDim.x * 256;
  // ---- weight prep (grid-stride; executes once for low gids) ----
  for (int idx = gid; idx < 128 * 96; idx += np) {
    int n = idx & 127, kk = idx >> 7;
    float w = (n < 64) ? Wkv[kk * 128 + 2 * n] : Wkv[kk * 128 + 2 * (n - 64) + 1];
    Bkvb[n * 104 + kk] = bf16_of(w);
  }
  for (int idx = gid; idx < 64 * 64; idx += np) {
    int n = idx & 63, kk = idx >> 6;
    W1tb[n * 88 + kk] = bf16_of(W1[kk * 64 + n]);
  }
  for (int idx = gid; idx < 32 * 64; idx += np) {
    int i2 = idx >> 6, j = idx & 63;
    Wqp[idx] = pack_bf(Wq[(2 * i2) * 64 + j], Wq[(2 * i2 + 1) * 64 + j]);
  }
  // ---- radial norm: 16 lanes per edge, shuffle-based (2 loads/lane) ----
  const int lane = threadIdx.x & 63;
  const int grp = lane >> 4, g = lane & 15;
  const int c4 = g >> 2, f4 = g & 3;
  const int wid = blockIdx.x * 4 + (threadIdx.x >> 6);
  const int nw = gridDim.x * 4;
  float acc = 0.f;
  for (int base = wid * 4; base < NE; base += nw * 4) {
    int e = base + grp;
    int r = row[e], c = col[e];
    float cd = 0.f;
    if (g < 12) cd = coord[r * 12 + g] - coord[c * 12 + g];
    float rad = 0.f;
#pragma unroll
    for (int d = 0; d < 3; ++d)
      rad += __shfl(cd, grp * 16 + c4 * 3 + d) * __shfl(cd, grp * 16 + f4 * 3 + d);
    acc += rad * rad;
    if (g == 0) atomicAdd(deg + r, 1);
  }
  acc += __shfl_xor(acc, 16);
  acc += __shfl_xor(acc, 32);
  if (lane < 16) atomicAdd(norm_acc + lane, acc);
}

// ---------- k_scanq: block 0 = CSR scan (+rnorm); blocks >=1 = q/hb ----------
__global__ __launch_bounds__(1024)
void k_scanq(const int* __restrict__ deg, int* __restrict__ startA,
             int* __restrict__ cursor, const float* __restrict__ norm_acc,
             float* __restrict__ rnorm, const float* __restrict__ h,
             const unsigned* __restrict__ Wqp, const float* __restrict__ bq,
             unsigned short* __restrict__ qg2, unsigned short* __restrict__ hb) {
  __shared__ int part[1024];
  __shared__ unsigned sWqp[32 * 64];
  __shared__ float sHr[16][64];
  const int t = threadIdx.x;
  if (blockIdx.x == 0) {
    if (t < 16) rnorm[t] = 1.0f / fmaxf(sqrtf(norm_acc[t]), 1e-12f);
    const int CH = (NN + 1023) / 1024;
    const int lo = t * CH, hi = (lo + CH < NN) ? lo + CH : NN;
    int s = 0;
    for (int i = lo; i < hi; ++i) s += deg[i];
    part[t] = s;
    __syncthreads();
    for (int off = 1; off < 1024; off <<= 1) {
      int v = (t >= off) ? part[t - off] : 0;
      __syncthreads();
      part[t] += v;
      __syncthreads();
    }
    int base = (t == 0) ? 0 : part[t - 1];
    for (int i = lo; i < hi; ++i) {
      startA[i] = base; cursor[i] = base; base += deg[i];
    }
    if (t == 1023) startA[NN] = base;
    return;
  }
  // ---- q = h@Wq + bq (permuted bf16) + hb (bf16 copy of h) ----
  for (int idx = t; idx < 2048; idx += 1024) sWqp[idx] = Wqp[idx];
  __syncthreads();
  const int wv = t >> 6, lane = t & 63;
  const int node = (blockIdx.x - 1) * 16 + wv;
  float hv = h[(size_t)node * 64 + lane];
  sHr[wv][lane] = hv;
  hb[(size_t)node * 64 + lane] = bf16_of(hv);
  float q = bq[lane];
  const float2* hp = (const float2*)sHr[wv];
#pragma unroll 8
  for (int i2 = 0; i2 < 32; ++i2) {
    unsigned w = sWqp[i2 * 64 + lane];
    float2 hbv = hp[i2];
    q += hbv.x * blo(w) + hbv.y * bhi(w);
  }
  qg2[(size_t)node * 64 + (lane & 15) * 4 + (lane >> 4)] = bf16_of(q);
}

__global__ void k_scatter(const int* __restrict__ row, int* __restrict__ cursor,
                          int* __restrict__ eperm) {
  int e = blockIdx.x * 256 + threadIdx.x;
  if (e < NE) {
    int p = atomicAdd(cursor + row[e], 1);
    eperm[p] = e;
  }
}

// ---------------- main MFMA GEMM over 64 CSR slots per block ----------------
__global__ __launch_bounds__(256, 3)
void k_kv(const unsigned short* __restrict__ hb, const float* __restrict__ coord,
          const int* __restrict__ row, const int* __restrict__ col,
          const float* __restrict__ edge_attr, const float* __restrict__ bkv,
          const float* __restrict__ b1, const float* __restrict__ W2,
          const float* __restrict__ rnorm, const int* __restrict__ eperm,
          const unsigned short* __restrict__ Bkvb,
          const unsigned short* __restrict__ W1tb,
          const unsigned short* __restrict__ qg2,
          float* __restrict__ exg, unsigned short* __restrict__ vg,
          unsigned short* __restrict__ transg) {
  __shared__ __align__(16) unsigned short sA[64][104];   // feat bf16; later v
  __shared__ __align__(16) unsigned short sB[128][104];  // [k|v]^T bf16
  __shared__ __align__(16) unsigned short sW1t[64][88];  // W1^T bf16
  __shared__ unsigned short cdb[64][12];                 // coord_diff bf16
  __shared__ int sCol[64], sRow[64], sE[64];

  const int tid = threadIdx.x;
  const int base = blockIdx.x * 64;

  if (tid < 64) {
    int e = eperm[base + tid];
    sE[tid] = e; sCol[tid] = col[e]; sRow[tid] = row[e];
  }
  // weights: pure vector copies (L2-hot)
  {
    const uint4* gb = (const uint4*)Bkvb;
    uint4* sb = (uint4*)&sB[0][0];
    for (int idx = tid; idx < 1664; idx += 256) sb[idx] = gb[idx];
    const uint4* gw = (const uint4*)W1tb;
    uint4* sw = (uint4*)&sW1t[0][0];
    for (int idx = tid; idx < 704; idx += 256) sw[idx] = gw[idx];
  }
  __syncthreads();   // sCol/sRow/sE visible

  // h[col] gather from bf16 copy: 64 rows x 8 uint4 (128B/row)
  for (int idx = tid; idx < 512; idx += 256) {
    int s = idx >> 3, q8 = idx & 7;
    uint4 u = ((const uint4*)(hb + (size_t)sCol[s] * 64))[q8];
    *(uint4*)&sA[s][16 + q8 * 8] = u;
  }
  // edge_attr: 64 rows x 8 dword-cols (pairwise pack)
  for (int idx = tid; idx < 512; idx += 256) {
    int s = idx >> 3, c2 = idx & 7;
    float2 ea = ((const float2*)(edge_attr + (size_t)sE[s] * 16))[c2];
    *(unsigned*)&sA[s][80 + 2 * c2] = pack_bf(ea.x, ea.y);
  }
  // radial + cdb via register shuffles
  {
    const int wv = tid >> 6, lane = tid & 63;
    const int grp = lane >> 4, g = lane & 15;
    const int c4 = g >> 2, f4 = g & 3;
    const float rn = rnorm[g];
#pragma unroll
    for (int it = 0; it < 4; ++it) {
      int slot = 16 * wv + it * 4 + grp;
      int r = sRow[slot], c = sCol[slot];
      float cd = 0.f;
      if (g < 12) cd = coord[r * 12 + g] - coord[c * 12 + g];
      float rad = 0.f;
#pragma unroll
      for (int d = 0; d < 3; ++d)
        rad += __shfl(cd, grp * 16 + c4 * 3 + d) * __shfl(cd, grp * 16 + f4 * 3 + d);
      sA[slot][g] = bf16_of(rad * rn);
      if (g < 12) cdb[slot][g] = bf16_of(cd);
    }
  }
  __syncthreads();   // sA complete

  const int wv = tid >> 6, lane = tid & 63;
  const int m16 = lane & 15, quad = lane >> 4;
  const int arow = 16 * wv + m16;

  // kv = feat @ [Wk|Wv]
  floatx4 acc[8];
#pragma unroll
  for (int i = 0; i < 8; ++i) acc[i] = (floatx4){0.f, 0.f, 0.f, 0.f};
#pragma unroll
  for (int ks = 0; ks < 3; ++ks) {
    short8 af = *(const short8*)&sA[arow][ks * 32 + quad * 8];
#pragma unroll
    for (int nt = 0; nt < 8; ++nt) {
      short8 bf = *(const short8*)&sB[nt * 16 + m16][ks * 32 + quad * 8];
      acc[nt] = __builtin_amdgcn_mfma_f32_16x16x32_bf16(af, bf, acc[nt], 0, 0, 0);
    }
  }
#pragma unroll
  for (int nt = 0; nt < 4; ++nt) {
    float bk = bkv[2 * (m16 + 16 * nt)];
    float bv = bkv[2 * (m16 + 16 * nt) + 1];
#pragma unroll
    for (int r = 0; r < 4; ++r) { acc[nt][r] += bk; acc[nt + 4][r] += bv; }
  }
  // alpha = q . k -> ex = exp(alpha)   (no max stabilizer: |alpha| << 88)
  float part[4] = {0.f, 0.f, 0.f, 0.f};
#pragma unroll
  for (int r = 0; r < 4; ++r) {
    int nrow = sRow[16 * wv + quad * 4 + r];
    uint2 qp = *(const uint2*)(qg2 + (size_t)nrow * 64 + m16 * 4);
    part[r] += blo(qp.x) * acc[0][r] + bhi(qp.x) * acc[1][r] +
               blo(qp.y) * acc[2][r] + bhi(qp.y) * acc[3][r];
  }
#pragma unroll
  for (int off = 1; off < 16; off <<= 1) {
#pragma unroll
    for (int r = 0; r < 4; ++r) part[r] += __shfl_xor(part[r], off);
  }
  if (m16 == 0) {
#pragma unroll
    for (int r = 0; r < 4; ++r)
      exg[base + 16 * wv + quad * 4 + r] = __expf(part[r]);
  }
  // v -> sA rows (wave-private), then linear global write
#pragma unroll
  for (int nt = 0; nt < 4; ++nt)
#pragma unroll
    for (int r = 0; r < 4; ++r)
      sA[16 * wv + quad * 4 + r][m16 + 16 * nt] = bf16_of(acc[4 + nt][r]);
  for (int i = lane; i < 16 * 32; i += 64) {
    int r = i >> 5, dw = i & 31;
    unsigned u = *(const unsigned*)&sA[16 * wv + r][dw * 2];
    ((unsigned*)vg)[(size_t)(base + 16 * wv + r) * 32 + dw] = u;
  }
  // t = silu(v @ W1 + b1)
  floatx4 tacc[4];
#pragma unroll
  for (int i = 0; i < 4; ++i) tacc[i] = (floatx4){0.f, 0.f, 0.f, 0.f};
#pragma unroll
  for (int ks = 0; ks < 2; ++ks) {
    short8 af = *(const short8*)&sA[arow][ks * 32 + quad * 8];
#pragma unroll
    for (int nt = 0; nt < 4; ++nt) {
      short8 bf = *(const short8*)&sW1t[nt * 16 + m16][ks * 32 + quad * 8];
      tacc[nt] = __builtin_amdgcn_mfma_f32_16x16x32_bf16(af, bf, tacc[nt], 0, 0, 0);
    }
  }
#pragma unroll
  for (int nt = 0; nt < 4; ++nt) {
    float bb = b1[m16 + 16 * nt];
#pragma unroll
    for (int r = 0; r < 4; ++r) {
      float t = tacc[nt][r] + bb;
      tacc[nt][r] = t / (1.f + __expf(-t));
    }
  }
  // cv = t @ W2 (all-reduce across the 16-lane group)
  float cvp[4][4];
#pragma unroll
  for (int r = 0; r < 4; ++r)
#pragma unroll
    for (int c = 0; c < 4; ++c) cvp[r][c] = 0.f;
#pragma unroll
  for (int nt = 0; nt < 4; ++nt) {
    float4 w2r = ((const float4*)W2)[m16 + 16 * nt];
#pragma unroll
    for (int r = 0; r < 4; ++r) {
      cvp[r][0] += tacc[nt][r] * w2r.x;
      cvp[r][1] += tacc[nt][r] * w2r.y;
      cvp[r][2] += tacc[nt][r] * w2r.z;
      cvp[r][3] += tacc[nt][r] * w2r.w;
    }
  }
#pragma unroll
  for (int off = 1; off < 16; off <<= 1) {
#pragma unroll
    for (int r = 0; r < 4; ++r)
#pragma unroll
      for (int c = 0; c < 4; ++c) cvp[r][c] += __shfl_xor(cvp[r][c], off);
  }
  // trans = cd * cv  (bf16)
#pragma unroll
  for (int r = 0; r < 4; ++r) {
    int row16 = quad * 4 + r;
    if (m16 < 12) {
      float cvv = (m16 < 3) ? cvp[r][0] : (m16 < 6) ? cvp[r][1]
                : (m16 < 9) ? cvp[r][2] : cvp[r][3];
      float cdv = bf2f(cdb[16 * wv + row16][m16]);
      transg[(size_t)(base + 16 * wv + row16) * 12 + m16] = bf16_of(cdv * cvv);
    }
  }
}

// ---------------- per-node accumulate (single streaming pass) --------------
__global__ __launch_bounds__(256)
void k_accum(const float* __restrict__ h, const float* __restrict__ coord,
             const int* __restrict__ startA, const int* __restrict__ eperm,
             const float* __restrict__ exg,
             const unsigned short* __restrict__ vg,
             const unsigned short* __restrict__ transg,
             float* __restrict__ out) {
  const int wv = threadIdx.x >> 6, lane = threadIdx.x & 63;
  const int node = blockIdx.x * 4 + wv;
  const int s0 = startA[node], s1 = startA[node + 1];

  float l = 0.f, h0 = 0.f, h1 = 0.f, c0 = 0.f, c1 = 0.f;
  int j = s0;
  for (; j + 1 < s1; j += 2) {
    float e0 = exg[j], e1 = exg[j + 1];
    float va = bf2f(vg[(size_t)j * 64 + lane]);
    float vb = bf2f(vg[(size_t)(j + 1) * 64 + lane]);
    float ta = (lane < 12) ? bf2f(transg[(size_t)j * 12 + lane]) : 0.f;
    float tb = (lane < 12) ? bf2f(transg[(size_t)(j + 1) * 12 + lane]) : 0.f;
    l += e0 + e1;
    h0 += e0 * va; h1 += e1 * vb;
    c0 += e0 * ta; c1 += e1 * tb;
  }
  if (j < s1) {
    float e0 = exg[j];
    float va = bf2f(vg[(size_t)j * 64 + lane]);
    float ta = (lane < 12) ? bf2f(transg[(size_t)j * 12 + lane]) : 0.f;
    l += e0; h0 += e0 * va; c0 += e0 * ta;
  }
  float hacc = h0 + h1, cacc = c0 + c1;
  const float inv = (l > 0.f) ? 1.f / l : 0.f;
  out[node * 64 + lane] = h[node * 64 + lane] + hacc * inv;
  if (lane < 12)
    out[NN * 64 + node * 12 + lane] = coord[node * 12 + lane] + cacc * inv;
  for (int j2 = s0 + lane; j2 < s1; j2 += 64)
    out[NN * 64 + NN * 12 + eperm[j2]] = exg[j2] * inv;
}

extern "C" void kernel_launch(void* const* d_in, const int* in_sizes, int n_in,
                              void* d_out, int out_size, void* d_ws, size_t ws_size,
                              hipStream_t stream) {
  const float* h         = (const float*)d_in[0];
  const float* coord     = (const float*)d_in[1];
  const int*   row       = (const int*)d_in[2];
  const int*   col       = (const int*)d_in[3];
  const float* edge_attr = (const float*)d_in[4];
  const float* Wq        = (const float*)d_in[5];
  const float* bq        = (const float*)d_in[6];
  const float* Wkv       = (const float*)d_in[7];
  const float* bkv       = (const float*)d_in[8];
  const float* W1        = (const float*)d_in[9];
  const float* b1        = (const float*)d_in[10];
  const float* W2        = (const float*)d_in[11];
  float* out = (float*)d_out;

  size_t off = 0;
  char* wsb = (char*)d_ws;
  auto alloc = [&](size_t bytes) {
    off = (off + 255) & ~(size_t)255;
    void* p = wsb + off; off += bytes; return p;
  };
  // ---- zeroed region (contiguous, one memset) ----
  float*          norm_acc = (float*)alloc(16 * 4);
  int*            deg      = (int*)alloc((size_t)NN * 4);
  size_t zbytes = off;
  // ---- rest ----
  float*          rnorm    = (float*)alloc(16 * 4);
  int*            startA   = (int*)alloc(((size_t)NN + 1) * 4);
  int*            cursor   = (int*)alloc((size_t)NN * 4);
  int*            eperm    = (int*)alloc((size_t)NE * 4);
  float*          exg      = (float*)alloc((size_t)NE * 4);
  unsigned short* qg2      = (unsigned short*)alloc((size_t)NN * 64 * 2);
  unsigned short* hb       = (unsigned short*)alloc((size_t)NN * 64 * 2);
  unsigned short* Bkvb     = (unsigned short*)alloc(128 * 104 * 2);
  unsigned short* W1tb     = (unsigned short*)alloc(64 * 88 * 2);
  unsigned*       Wqp      = (unsigned*)alloc(32 * 64 * 4);
  unsigned short* transg   = (unsigned short*)alloc((size_t)NE * 12 * 2);
  unsigned short* vg       = (unsigned short*)alloc((size_t)NE * 64 * 2);

  hipMemsetAsync(d_ws, 0, zbytes, stream);

  k_pre<<<1024, 256, 0, stream>>>(coord, row, col, Wkv, W1, Wq,
                                  norm_acc, deg, Bkvb, W1tb, Wqp);
  k_scanq<<<1 + NN / 16, 1024, 0, stream>>>(deg, startA, cursor, norm_acc,
                                            rnorm, h, Wqp, bq, qg2, hb);
  k_scatter<<<(NE + 255) / 256, 256, 0, stream>>>(row, cursor, eperm);
  k_kv<<<NE / 64, 256, 0, stream>>>(hb, coord, row, col, edge_attr, bkv, b1, W2,
                                    rnorm, eperm, Bkvb, W1tb, qg2,
                                    exg, vg, transg);
  k_accum<<<NN / 4, 256, 0, stream>>>(h, coord, startA, eperm, exg, vg,
                                      transg, out);
}

// Round 8
// 621.307 us; speedup vs baseline: 1.1441x; 1.0248x over previous
//
#include <hip/hip_runtime.h>
#include <math.h>

#define NN 50000
#define NE 800000

typedef __attribute__((ext_vector_type(8))) short short8;
typedef __attribute__((ext_vector_type(4))) float floatx4;

__device__ __forceinline__ unsigned short bf16_of(float x) {
  unsigned u = __float_as_uint(x);
  u += 0x7fffu + ((u >> 16) & 1u);
  return (unsigned short)(u >> 16);
}
__device__ __forceinline__ float bf2f(unsigned short u) {
  return __uint_as_float(((unsigned)u) << 16);
}
__device__ __forceinline__ unsigned pack_bf(float a, float b) {
  unsigned ua = __float_as_uint(a); ua += 0x7fffu + ((ua >> 16) & 1u);
  unsigned ub = __float_as_uint(b); ub += 0x7fffu + ((ub >> 16) & 1u);
  return (ua >> 16) | (ub & 0xffff0000u);
}
__device__ __forceinline__ float blo(unsigned w) { return __uint_as_float(w << 16); }
__device__ __forceinline__ float bhi(unsigned w) { return __uint_as_float(w & 0xffff0000u); }

// ---------- k_pre: weight conversion + radial-norm + degree count ----------
__global__ __launch_bounds__(256)
void k_pre(const float* __restrict__ coord, const int* __restrict__ row,
           const int* __restrict__ col, const float* __restrict__ Wkv,
           const float* __restrict__ W1, const float* __restrict__ Wq,
           float* __restrict__ norm_acc, int* __restrict__ deg,
           unsigned short* __restrict__ Bkvb, unsigned short* __restrict__ W1tb,
           unsigned* __restrict__ Wqp) {
  const int gid = blockIdx.x * 256 + threadIdx.x;
  const int np = gridDim.x * 256;
  for (int idx = gid; idx < 128 * 96; idx += np) {
    int n = idx & 127, kk = idx >> 7;
    float w = (n < 64) ? Wkv[kk * 128 + 2 * n] : Wkv[kk * 128 + 2 * (n - 64) + 1];
    Bkvb[n * 104 + kk] = bf16_of(w);
  }
  for (int idx = gid; idx < 64 * 64; idx += np) {
    int n = idx & 63, kk = idx >> 6;
    W1tb[n * 88 + kk] = bf16_of(W1[kk * 64 + n]);
  }
  for (int idx = gid; idx < 32 * 64; idx += np) {
    int i2 = idx >> 6, j = idx & 63;
    Wqp[idx] = pack_bf(Wq[(2 * i2) * 64 + j], Wq[(2 * i2 + 1) * 64 + j]);
  }
  const int lane = threadIdx.x & 63;
  const int grp = lane >> 4, g = lane & 15;
  const int c4 = g >> 2, f4 = g & 3;
  const int wid = blockIdx.x * 4 + (threadIdx.x >> 6);
  const int nw = gridDim.x * 4;
  float acc = 0.f;
  for (int base = wid * 4; base < NE; base += nw * 4) {
    int e = base + grp;
    int r = row[e], c = col[e];
    float cd = 0.f;
    if (g < 12) cd = coord[r * 12 + g] - coord[c * 12 + g];
    float rad = 0.f;
#pragma unroll
    for (int d = 0; d < 3; ++d)
      rad += __shfl(cd, grp * 16 + c4 * 3 + d) * __shfl(cd, grp * 16 + f4 * 3 + d);
    acc += rad * rad;
    if (g == 0) atomicAdd(deg + r, 1);
  }
  acc += __shfl_xor(acc, 16);
  acc += __shfl_xor(acc, 32);
  if (lane < 16) atomicAdd(norm_acc + lane, acc);
}

// ---------- k_scanq: block 0 = CSR scan (+rnorm); blocks >=1 = q/hb ----------
__global__ __launch_bounds__(1024)
void k_scanq(const int* __restrict__ deg, int* __restrict__ startA,
             int* __restrict__ cursor, const float* __restrict__ norm_acc,
             float* __restrict__ rnorm, const float* __restrict__ h,
             const unsigned* __restrict__ Wqp, const float* __restrict__ bq,
             unsigned short* __restrict__ qg2, unsigned short* __restrict__ hb) {
  __shared__ int part[1024];
  __shared__ unsigned sWqp[32 * 64];
  __shared__ float sHr[16][64];
  const int t = threadIdx.x;
  if (blockIdx.x == 0) {
    if (t < 16) rnorm[t] = 1.0f / fmaxf(sqrtf(norm_acc[t]), 1e-12f);
    const int CH = (NN + 1023) / 1024;
    const int lo = t * CH, hi = (lo + CH < NN) ? lo + CH : NN;
    int s = 0;
    for (int i = lo; i < hi; ++i) s += deg[i];
    part[t] = s;
    __syncthreads();
    for (int off = 1; off < 1024; off <<= 1) {
      int v = (t >= off) ? part[t - off] : 0;
      __syncthreads();
      part[t] += v;
      __syncthreads();
    }
    int base = (t == 0) ? 0 : part[t - 1];
    for (int i = lo; i < hi; ++i) {
      startA[i] = base; cursor[i] = base; base += deg[i];
    }
    if (t == 1023) startA[NN] = base;
    return;
  }
  for (int idx = t; idx < 2048; idx += 1024) sWqp[idx] = Wqp[idx];
  __syncthreads();
  const int wv = t >> 6, lane = t & 63;
  const int node = (blockIdx.x - 1) * 16 + wv;
  float hv = h[(size_t)node * 64 + lane];
  sHr[wv][lane] = hv;
  hb[(size_t)node * 64 + lane] = bf16_of(hv);
  float q = bq[lane];
  const float2* hp = (const float2*)sHr[wv];
#pragma unroll 8
  for (int i2 = 0; i2 < 32; ++i2) {
    unsigned w = sWqp[i2 * 64 + lane];
    float2 hbv = hp[i2];
    q += hbv.x * blo(w) + hbv.y * bhi(w);
  }
  qg2[(size_t)node * 64 + (lane & 15) * 4 + (lane >> 4)] = bf16_of(q);
}

__global__ void k_scatter(const int* __restrict__ row, int* __restrict__ cursor,
                          int* __restrict__ eperm) {
  int e = blockIdx.x * 256 + threadIdx.x;
  if (e < NE) {
    int p = atomicAdd(cursor + row[e], 1);
    eperm[p] = e;
  }
}

// -------- main fused kernel: GEMM + per-wave segment reduce + atomics -------
__global__ __launch_bounds__(256, 3)
void k_kv(const unsigned short* __restrict__ hb, const float* __restrict__ coord,
          const int* __restrict__ row, const int* __restrict__ col,
          const float* __restrict__ edge_attr, const float* __restrict__ bkv,
          const float* __restrict__ b1, const float* __restrict__ W2,
          const float* __restrict__ rnorm, const int* __restrict__ eperm,
          const unsigned short* __restrict__ Bkvb,
          const unsigned short* __restrict__ W1tb,
          const unsigned short* __restrict__ qg2,
          float* __restrict__ exg, float* __restrict__ l_g,
          float* __restrict__ hacc_g, float* __restrict__ cacc_g) {
  __shared__ __align__(16) unsigned short sA[64][104];   // feat bf16; later v
  __shared__ __align__(16) unsigned short sB[128][104];  // [k|v]^T bf16
  __shared__ __align__(16) unsigned short sW1t[64][88];  // W1^T bf16
  __shared__ unsigned short cdb[64][12];                 // coord_diff bf16
  __shared__ int sCol[64], sRow[64], sE[64];
  // LDS total 53504 B == R6/R7 footprint -> keeps 3 blocks/CU (the cliff!)

  const int tid = threadIdx.x;
  const int base = blockIdx.x * 64;

  if (tid < 64) {
    int e = eperm[base + tid];
    sE[tid] = e; sCol[tid] = col[e]; sRow[tid] = row[e];
  }
  {
    const uint4* gb = (const uint4*)Bkvb;
    uint4* sb = (uint4*)&sB[0][0];
    for (int idx = tid; idx < 1664; idx += 256) sb[idx] = gb[idx];
    const uint4* gw = (const uint4*)W1tb;
    uint4* sw = (uint4*)&sW1t[0][0];
    for (int idx = tid; idx < 704; idx += 256) sw[idx] = gw[idx];
  }
  __syncthreads();   // sCol/sRow/sE visible

  for (int idx = tid; idx < 512; idx += 256) {
    int s = idx >> 3, q8 = idx & 7;
    uint4 u = ((const uint4*)(hb + (size_t)sCol[s] * 64))[q8];
    *(uint4*)&sA[s][16 + q8 * 8] = u;
  }
  for (int idx = tid; idx < 512; idx += 256) {
    int s = idx >> 3, c2 = idx & 7;
    float2 ea = ((const float2*)(edge_attr + (size_t)sE[s] * 16))[c2];
    *(unsigned*)&sA[s][80 + 2 * c2] = pack_bf(ea.x, ea.y);
  }
  {
    const int wv = tid >> 6, lane = tid & 63;
    const int grp = lane >> 4, g = lane & 15;
    const int c4 = g >> 2, f4 = g & 3;
    const float rn = rnorm[g];
#pragma unroll
    for (int it = 0; it < 4; ++it) {
      int slot = 16 * wv + it * 4 + grp;
      int r = sRow[slot], c = sCol[slot];
      float cd = 0.f;
      if (g < 12) cd = coord[r * 12 + g] - coord[c * 12 + g];
      float rad = 0.f;
#pragma unroll
      for (int d = 0; d < 3; ++d)
        rad += __shfl(cd, grp * 16 + c4 * 3 + d) * __shfl(cd, grp * 16 + f4 * 3 + d);
      sA[slot][g] = bf16_of(rad * rn);
      if (g < 12) cdb[slot][g] = bf16_of(cd);
    }
  }
  __syncthreads();   // sA complete

  const int wv = tid >> 6, lane = tid & 63;
  const int m16 = lane & 15, quad = lane >> 4;
  const int arow = 16 * wv + m16;

  // kv = feat @ [Wk|Wv]
  floatx4 acc[8];
#pragma unroll
  for (int i = 0; i < 8; ++i) acc[i] = (floatx4){0.f, 0.f, 0.f, 0.f};
#pragma unroll
  for (int ks = 0; ks < 3; ++ks) {
    short8 af = *(const short8*)&sA[arow][ks * 32 + quad * 8];
#pragma unroll
    for (int nt = 0; nt < 8; ++nt) {
      short8 bf = *(const short8*)&sB[nt * 16 + m16][ks * 32 + quad * 8];
      acc[nt] = __builtin_amdgcn_mfma_f32_16x16x32_bf16(af, bf, acc[nt], 0, 0, 0);
    }
  }
#pragma unroll
  for (int nt = 0; nt < 4; ++nt) {
    float bk = bkv[2 * (m16 + 16 * nt)];
    float bv = bkv[2 * (m16 + 16 * nt) + 1];
#pragma unroll
    for (int r = 0; r < 4; ++r) { acc[nt][r] += bk; acc[nt + 4][r] += bv; }
  }
  // alpha = q . k -> ex = exp(alpha)   (no max stabilizer: |alpha| << 88)
  float part[4] = {0.f, 0.f, 0.f, 0.f};
#pragma unroll
  for (int r = 0; r < 4; ++r) {
    int nrow = sRow[16 * wv + quad * 4 + r];
    uint2 qp = *(const uint2*)(qg2 + (size_t)nrow * 64 + m16 * 4);
    part[r] += blo(qp.x) * acc[0][r] + bhi(qp.x) * acc[1][r] +
               blo(qp.y) * acc[2][r] + bhi(qp.y) * acc[3][r];
  }
#pragma unroll
  for (int off = 1; off < 16; off <<= 1) {
#pragma unroll
    for (int r = 0; r < 4; ++r) part[r] += __shfl_xor(part[r], off);
  }
  float ex[4];
#pragma unroll
  for (int r = 0; r < 4; ++r) ex[r] = __expf(part[r]);
  if (m16 == 0) {
#pragma unroll
    for (int r = 0; r < 4; ++r)
      exg[base + 16 * wv + quad * 4 + r] = ex[r];
  }
  // v (bf16) -> sA rows (wave-private) for the W1 GEMM; keep fp32 v in acc[4..7]
#pragma unroll
  for (int nt = 0; nt < 4; ++nt)
#pragma unroll
    for (int r = 0; r < 4; ++r)
      sA[16 * wv + quad * 4 + r][m16 + 16 * nt] = bf16_of(acc[4 + nt][r]);
  // t = silu(v @ W1 + b1)
  floatx4 tacc[4];
#pragma unroll
  for (int i = 0; i < 4; ++i) tacc[i] = (floatx4){0.f, 0.f, 0.f, 0.f};
#pragma unroll
  for (int ks = 0; ks < 2; ++ks) {
    short8 af = *(const short8*)&sA[arow][ks * 32 + quad * 8];
#pragma unroll
    for (int nt = 0; nt < 4; ++nt) {
      short8 bf = *(const short8*)&sW1t[nt * 16 + m16][ks * 32 + quad * 8];
      tacc[nt] = __builtin_amdgcn_mfma_f32_16x16x32_bf16(af, bf, tacc[nt], 0, 0, 0);
    }
  }
#pragma unroll
  for (int nt = 0; nt < 4; ++nt) {
    float bb = b1[m16 + 16 * nt];
#pragma unroll
    for (int r = 0; r < 4; ++r) {
      float t = tacc[nt][r] + bb;
      tacc[nt][r] = t / (1.f + __expf(-t));
    }
  }
  // cv = t @ W2 (all-reduce across the 16-lane group)
  float cvp[4][4];
#pragma unroll
  for (int r = 0; r < 4; ++r)
#pragma unroll
    for (int c = 0; c < 4; ++c) cvp[r][c] = 0.f;
#pragma unroll
  for (int nt = 0; nt < 4; ++nt) {
    float4 w2r = ((const float4*)W2)[m16 + 16 * nt];
#pragma unroll
    for (int r = 0; r < 4; ++r) {
      cvp[r][0] += tacc[nt][r] * w2r.x;
      cvp[r][1] += tacc[nt][r] * w2r.y;
      cvp[r][2] += tacc[nt][r] * w2r.z;
      cvp[r][3] += tacc[nt][r] * w2r.w;
    }
  }
#pragma unroll
  for (int off = 1; off < 16; off <<= 1) {
#pragma unroll
    for (int r = 0; r < 4; ++r)
#pragma unroll
      for (int c = 0; c < 4; ++c) cvp[r][c] += __shfl_xor(cvp[r][c], off);
  }
  // trans per row (register): tr[r] = cd * cv  for dim m16 (<12)
  float tr[4];
#pragma unroll
  for (int r = 0; r < 4; ++r) {
    if (m16 < 12) {
      float cvv = (m16 < 3) ? cvp[r][0] : (m16 < 6) ? cvp[r][1]
                : (m16 < 9) ? cvp[r][2] : cvp[r][3];
      tr[r] = bf2f(cdb[16 * wv + quad * 4 + r][m16]) * cvv;
    } else tr[r] = 0.f;
  }

  // ---- per-wave segment reduce over this wave's 16 slots + atomics ----
  int s = 0;
  while (s < 16) {
    int n = sRow[16 * wv + s];                    // uniform (broadcast)
    int e2 = s + 1;
    while (e2 < 16 && sRow[16 * wv + e2] == n) ++e2;
    float hp0 = 0.f, hp1 = 0.f, hp2 = 0.f, hp3 = 0.f, lp = 0.f, cp = 0.f;
#pragma unroll
    for (int r = 0; r < 4; ++r) {
      int rowi = quad * 4 + r;
      float w = (rowi >= s && rowi < e2) ? ex[r] : 0.f;
      hp0 += w * acc[4][r];
      hp1 += w * acc[5][r];
      hp2 += w * acc[6][r];
      hp3 += w * acc[7][r];
      lp  += (rowi >= s && rowi < e2) ? ex[r] : 0.f;
      cp  += w * tr[r];
    }
    // cross-quad reduce (lanes differing only in bits 4,5)
    hp0 += __shfl_xor(hp0, 16); hp0 += __shfl_xor(hp0, 32);
    hp1 += __shfl_xor(hp1, 16); hp1 += __shfl_xor(hp1, 32);
    hp2 += __shfl_xor(hp2, 16); hp2 += __shfl_xor(hp2, 32);
    hp3 += __shfl_xor(hp3, 16); hp3 += __shfl_xor(hp3, 32);
    lp  += __shfl_xor(lp, 16);  lp  += __shfl_xor(lp, 32);
    cp  += __shfl_xor(cp, 16);  cp  += __shfl_xor(cp, 32);
    if (quad == 0) {
      float* hg = hacc_g + (size_t)n * 64;
      atomicAdd(hg + m16,      hp0);
      atomicAdd(hg + m16 + 16, hp1);
      atomicAdd(hg + m16 + 32, hp2);
      atomicAdd(hg + m16 + 48, hp3);
      if (m16 < 12) atomicAdd(cacc_g + (size_t)n * 12 + m16, cp);
      if (m16 == 0) atomicAdd(l_g + n, lp);
    }
    s = e2;
  }
}

// ---------------- finalize ----------------
__global__ __launch_bounds__(256)
void k_fin(const float* __restrict__ h, const float* __restrict__ coord,
           const int* __restrict__ startA, const int* __restrict__ eperm,
           const float* __restrict__ exg, const float* __restrict__ l_g,
           const float* __restrict__ hacc_g, const float* __restrict__ cacc_g,
           float* __restrict__ out) {
  const int wv = threadIdx.x >> 6, lane = threadIdx.x & 63;
  const int node = blockIdx.x * 4 + wv;
  const float l = l_g[node];
  const float inv = (l > 0.f) ? 1.f / l : 0.f;
  out[node * 64 + lane] =
      h[(size_t)node * 64 + lane] + hacc_g[(size_t)node * 64 + lane] * inv;
  if (lane < 12)
    out[NN * 64 + node * 12 + lane] =
        coord[node * 12 + lane] + cacc_g[(size_t)node * 12 + lane] * inv;
  const int s0 = startA[node], s1 = startA[node + 1];
  for (int j = s0 + lane; j < s1; j += 64)
    out[NN * 64 + NN * 12 + eperm[j]] = exg[j] * inv;
}

extern "C" void kernel_launch(void* const* d_in, const int* in_sizes, int n_in,
                              void* d_out, int out_size, void* d_ws, size_t ws_size,
                              hipStream_t stream) {
  const float* h         = (const float*)d_in[0];
  const float* coord     = (const float*)d_in[1];
  const int*   row       = (const int*)d_in[2];
  const int*   col       = (const int*)d_in[3];
  const float* edge_attr = (const float*)d_in[4];
  const float* Wq        = (const float*)d_in[5];
  const float* bq        = (const float*)d_in[6];
  const float* Wkv       = (const float*)d_in[7];
  const float* bkv       = (const float*)d_in[8];
  const float* W1        = (const float*)d_in[9];
  const float* b1        = (const float*)d_in[10];
  const float* W2        = (const float*)d_in[11];
  float* out = (float*)d_out;

  size_t off = 0;
  char* wsb = (char*)d_ws;
  auto alloc = [&](size_t bytes) {
    off = (off + 255) & ~(size_t)255;
    void* p = wsb + off; off += bytes; return p;
  };
  // ---- zeroed region (contiguous, one memset) ----
  float*          norm_acc = (float*)alloc(16 * 4);
  int*            deg      = (int*)alloc((size_t)NN * 4);
  float*          l_g      = (float*)alloc((size_t)NN * 4);
  float*          hacc_g   = (float*)alloc((size_t)NN * 64 * 4);
  float*          cacc_g   = (float*)alloc((size_t)NN * 12 * 4);
  size_t zbytes = off;
  // ---- rest ----
  float*          rnorm    = (float*)alloc(16 * 4);
  int*            startA   = (int*)alloc(((size_t)NN + 1) * 4);
  int*            cursor   = (int*)alloc((size_t)NN * 4);
  int*            eperm    = (int*)alloc((size_t)NE * 4);
  float*          exg      = (float*)alloc((size_t)NE * 4);
  unsigned short* qg2      = (unsigned short*)alloc((size_t)NN * 64 * 2);
  unsigned short* hb       = (unsigned short*)alloc((size_t)NN * 64 * 2);
  unsigned short* Bkvb     = (unsigned short*)alloc(128 * 104 * 2);
  unsigned short* W1tb     = (unsigned short*)alloc(64 * 88 * 2);
  unsigned*       Wqp      = (unsigned*)alloc(32 * 64 * 4);

  hipMemsetAsync(d_ws, 0, zbytes, stream);

  k_pre<<<1024, 256, 0, stream>>>(coord, row, col, Wkv, W1, Wq,
                                  norm_acc, deg, Bkvb, W1tb, Wqp);
  k_scanq<<<1 + NN / 16, 1024, 0, stream>>>(deg, startA, cursor, norm_acc,
                                            rnorm, h, Wqp, bq, qg2, hb);
  k_scatter<<<(NE + 255) / 256, 256, 0, stream>>>(row, cursor, eperm);
  k_kv<<<NE / 64, 256, 0, stream>>>(hb, coord, row, col, edge_attr, bkv, b1, W2,
                                    rnorm, eperm, Bkvb, W1tb, qg2,
                                    exg, l_g, hacc_g, cacc_g);
  k_fin<<<NN / 4, 256, 0, stream>>>(h, coord, startA, eperm, exg, l_g,
                                    hacc_g, cacc_g, out);
}